// Round 1
// baseline (123.211 us; speedup 1.0000x reference)
//
#include <hip/hip_runtime.h>

// Problem constants (match reference)
#define N_VOX     200000
#define N_CLUST   2000
#define CLUST_SIZE 100
#define N_EDGE    32000
#define N_FEAT    16

// One thread handles one (point, feature-quad): point p in [0, N_EDGE*200),
// quad fb in [0,4). Computes 4 features and stores one float4.
// Consecutive threads -> consecutive float4 stores -> fully coalesced.
__global__ __launch_bounds__(256) void edge_enc_kernel(
    const float* __restrict__ data,        // [N_VOX, 5]
    const int*   __restrict__ clusts,      // [N_CLUST, CLUST_SIZE]
    const int*   __restrict__ edge_index,  // [2, N_EDGE]
    const float* __restrict__ W,           // [5, 16]
    float*       __restrict__ out)         // [N_EDGE*200, 16]
{
    __shared__ float Ws[5 * N_FEAT];   // 80 floats
    if (threadIdx.x < 5 * N_FEAT) {
        Ws[threadIdx.x] = W[threadIdx.x];
    }
    __syncthreads();

    const unsigned total = (unsigned)N_EDGE * 2u * CLUST_SIZE * 4u;  // 25.6M quads
    unsigned gid    = blockIdx.x * blockDim.x + threadIdx.x;
    unsigned stride = gridDim.x * blockDim.x;

    for (; gid < total; gid += stride) {
        const unsigned fb = gid & 3u;       // feature quad 0..3
        const unsigned p  = gid >> 2;       // point id 0..6.4M
        const unsigned e  = p / 200u;       // edge id (magic-mul)
        const unsigned j  = p - e * 200u;   // 0..199
        const unsigned side = (j >= 100u) ? 1u : 0u;
        const unsigned v    = j - side * 100u;

        const int c   = edge_index[side * N_EDGE + e];
        const int vox = clusts[c * CLUST_SIZE + (int)v];

        const float* dr = data + (size_t)vox * 5;
        const float x0 = dr[0];
        const float x1 = dr[1];
        const float x2 = dr[2];
        const float x3 = (float)e;      // batch-id column overwritten by edge id
        const float x4 = dr[4];

        const unsigned fbase = fb * 4u;
        float r[4];
#pragma unroll
        for (int q = 0; q < 4; ++q) {
            const unsigned f = fbase + q;
            float a = x0 * Ws[0 * N_FEAT + f]
                    + x1 * Ws[1 * N_FEAT + f]
                    + x2 * Ws[2 * N_FEAT + f]
                    + x3 * Ws[3 * N_FEAT + f]
                    + x4 * Ws[4 * N_FEAT + f];
            r[q] = fmaxf(a, 0.0f);
        }

        float4 ov = make_float4(r[0], r[1], r[2], r[3]);
        *reinterpret_cast<float4*>(out + (size_t)p * N_FEAT + fbase) = ov;
    }
}

extern "C" void kernel_launch(void* const* d_in, const int* in_sizes, int n_in,
                              void* d_out, int out_size, void* d_ws, size_t ws_size,
                              hipStream_t stream) {
    const float* data       = (const float*)d_in[0];
    const int*   clusts     = (const int*)d_in[1];
    const int*   edge_index = (const int*)d_in[2];
    const float* W          = (const float*)d_in[3];
    float*       out        = (float*)d_out;

    const int block = 256;
    const int grid  = 2048;   // grid-stride; ~48 iters/thread
    edge_enc_kernel<<<grid, block, 0, stream>>>(data, clusts, edge_index, W, out);
}

// Round 3
// 85.285 us; speedup vs baseline: 1.4447x; 1.4447x over previous
//
#include <hip/hip_runtime.h>

// Problem constants (match reference)
#define N_VOX      200000
#define N_CLUST    2000
#define CLUST_SIZE 100
#define N_EDGE     32000
#define N_FEAT     16

// Total output points = N_EDGE * 2 * CLUST_SIZE = 6.4M; each point has 16 feats.
// Work item ("quad") = (point, 4-feature group): 25.6M quads.
// Layout: 4 consecutive threads own one point -> each wave's float4 stores are
// a dense 1 KiB contiguous block (perfect coalescing).
//
// UNROLL=2: thread t handles quads t and t+HALF (HALF % 4 == 0, so both share
// the same feature quad fb -> W sub-column loaded once). Two independent
// 3-deep load chains in flight per thread.
//
// Output stores are NONTEMPORAL (native-vector type for the builtin):
// 409.6 MB write stream must not allocate in L2, else it evicts the 4 MB
// `data` gather working set (== one XCD's L2).

#define TOTAL_QUADS (N_EDGE * 2 * CLUST_SIZE * 4)   // 25,600,000
#define HALF_QUADS  (TOTAL_QUADS / 2)               // 12,800,000
#define BLOCK       256
#define GRID        (HALF_QUADS / BLOCK)            // 50,000

typedef float f32x4 __attribute__((ext_vector_type(4)));

__global__ __launch_bounds__(BLOCK) void edge_enc_kernel(
    const float* __restrict__ data,        // [N_VOX, 5]
    const int*   __restrict__ clusts,      // [N_CLUST, CLUST_SIZE]
    const int*   __restrict__ edge_index,  // [2, N_EDGE]
    const float* __restrict__ W,           // [5, 16]
    float*       __restrict__ out)         // [N_EDGE*200, 16]
{
    __shared__ float Ws[5 * N_FEAT];   // 80 floats
    if (threadIdx.x < 5 * N_FEAT) {
        Ws[threadIdx.x] = W[threadIdx.x];
    }
    __syncthreads();

    const unsigned t = blockIdx.x * BLOCK + threadIdx.x;    // 0 .. 12.8M-1

    // Both quads share fb since HALF_QUADS % 4 == 0.
    const unsigned fb    = t & 3u;
    const unsigned fbase = fb * 4u;

    // Load this thread's W sub-columns once (LDS broadcast reads).
    float w0[4], w1[4], w2[4], w3[4], w4[4];
#pragma unroll
    for (int q = 0; q < 4; ++q) {
        w0[q] = Ws[0 * N_FEAT + fbase + q];
        w1[q] = Ws[1 * N_FEAT + fbase + q];
        w2[q] = Ws[2 * N_FEAT + fbase + q];
        w3[q] = Ws[3 * N_FEAT + fbase + q];
        w4[q] = Ws[4 * N_FEAT + fbase + q];
    }

    // ---- index math for both quads (independent) ----
    const unsigned g0 = t;
    const unsigned g1 = t + (unsigned)HALF_QUADS;

    const unsigned p0 = g0 >> 2;
    const unsigned p1 = g1 >> 2;

    const unsigned e0 = p0 / 200u;                 // magic-mul
    const unsigned e1 = p1 / 200u;
    const unsigned j0 = p0 - e0 * 200u;
    const unsigned j1 = p1 - e1 * 200u;
    const unsigned s0 = (j0 >= 100u) ? 1u : 0u;
    const unsigned s1 = (j1 >= 100u) ? 1u : 0u;
    const unsigned v0 = j0 - s0 * 100u;
    const unsigned v1 = j1 - s1 * 100u;

    // ---- chain hop 1: edge_index (both issued back-to-back) ----
    const int c0 = edge_index[s0 * N_EDGE + e0];
    const int c1 = edge_index[s1 * N_EDGE + e1];

    // ---- chain hop 2: clusts ----
    const int vox0 = clusts[c0 * CLUST_SIZE + (int)v0];
    const int vox1 = clusts[c1 * CLUST_SIZE + (int)v1];

    // ---- chain hop 3: data rows ----
    const float* dr0 = data + (size_t)vox0 * 5;
    const float* dr1 = data + (size_t)vox1 * 5;
    const float a0 = dr0[0], a1 = dr0[1], a2 = dr0[2], a4 = dr0[4];
    const float b0 = dr1[0], b1 = dr1[1], b2 = dr1[2], b4 = dr1[4];
    const float a3 = (float)e0;   // batch-id column := edge id
    const float b3 = (float)e1;

    // ---- compute 4 feats each ----
    float ra[4], rb[4];
#pragma unroll
    for (int q = 0; q < 4; ++q) {
        float va = fmaf(a0, w0[q], fmaf(a1, w1[q], fmaf(a2, w2[q],
                   fmaf(a3, w3[q], a4 * w4[q]))));
        float vb = fmaf(b0, w0[q], fmaf(b1, w1[q], fmaf(b2, w2[q],
                   fmaf(b3, w3[q], b4 * w4[q]))));
        ra[q] = fmaxf(va, 0.0f);
        rb[q] = fmaxf(vb, 0.0f);
    }

    // ---- nontemporal dense stores (native vector type) ----
    f32x4 ova = { ra[0], ra[1], ra[2], ra[3] };
    f32x4 ovb = { rb[0], rb[1], rb[2], rb[3] };
    __builtin_nontemporal_store(ova,
        reinterpret_cast<f32x4*>(out + (size_t)p0 * N_FEAT + fbase));
    __builtin_nontemporal_store(ovb,
        reinterpret_cast<f32x4*>(out + (size_t)p1 * N_FEAT + fbase));
}

extern "C" void kernel_launch(void* const* d_in, const int* in_sizes, int n_in,
                              void* d_out, int out_size, void* d_ws, size_t ws_size,
                              hipStream_t stream) {
    const float* data       = (const float*)d_in[0];
    const int*   clusts     = (const int*)d_in[1];
    const int*   edge_index = (const int*)d_in[2];
    const float* W          = (const float*)d_in[3];
    float*       out        = (float*)d_out;

    edge_enc_kernel<<<GRID, BLOCK, 0, stream>>>(data, clusts, edge_index, W, out);
}